// Round 5
// baseline (181.494 us; speedup 1.0000x reference)
//
#include <hip/hip_runtime.h>
#include <hip/hip_bf16.h>

#define D 128            // D_IN == D_OUT
#define D2U 64           // D/2 packed bf16 pairs (uint) per row

typedef __attribute__((ext_vector_type(8))) short  short8;
typedef __attribute__((ext_vector_type(4))) float  f32x4;
typedef __attribute__((ext_vector_type(2))) float  f32x2;

// fp32 -> bf16 (RTNE)
__device__ __forceinline__ unsigned f2bf(float f) {
    unsigned u = __float_as_uint(f);
    u += 0x7FFFu + ((u >> 16) & 1u);
    return u >> 16;
}
__device__ __forceinline__ unsigned pk2(float a, float b) {
    return f2bf(a) | (f2bf(b) << 16);
}
__device__ __forceinline__ float bflo(unsigned u) { return __uint_as_float(u << 16); }
__device__ __forceinline__ float bfhi(unsigned u) { return __uint_as_float(u & 0xFFFF0000u); }

// ---------------------------------------------------------------------------
// Kernel 1: y = bf16(x @ W) via MFMA 16x16x32 bf16.  (unchanged from R4)
// ---------------------------------------------------------------------------
__global__ __launch_bounds__(256, 2) void gemm_mfma_kernel(
    const float* __restrict__ x, const float* __restrict__ W,
    unsigned* __restrict__ y, int n_nodes, int ntiles)
{
    __shared__ unsigned short Wt[D * D];   // bf16 [c][k], k XOR-swizzled, 32 KB

    const int t = threadIdx.x;

    // ---- transpose W fp32 [k][c] -> Wt bf16 [c][k] (slot = (k>>3) ^ (c&15))
    {
        const float4* W4 = reinterpret_cast<const float4*>(W);
#pragma unroll
        for (int m = 0; m < 16; ++m) {
            const int idx4 = m * 256 + t;        // float4 index
            const int k  = idx4 >> 5;            // 32 float4 per k-row
            const int c0 = (idx4 & 31) << 2;
            const float4 w = W4[idx4];
            const float wv[4] = {w.x, w.y, w.z, w.w};
#pragma unroll
            for (int i = 0; i < 4; ++i) {
                const int c    = c0 + i;
                const int slot = (k >> 3) ^ (c & 15);
                Wt[c * 128 + slot * 8 + (k & 7)] = (unsigned short)f2bf(wv[i]);
            }
        }
    }
    __syncthreads();

    const int lane = t & 63;
    const int cl   = lane & 15;
    const int g    = lane >> 4;

    // ---- hoist all W fragments (8 col-tiles x 4 k-steps) into registers
    short8 wf[8][4];
#pragma unroll
    for (int ct = 0; ct < 8; ++ct)
#pragma unroll
        for (int ks = 0; ks < 4; ++ks) {
            const int c    = ct * 16 + cl;
            const int slot = (ks * 4 + g) ^ cl;
            wf[ct][ks] = *reinterpret_cast<const short8*>(&Wt[c * 128 + slot * 8]);
        }

    const int wave   = (blockIdx.x << 2) | (t >> 6);
    const int nwaves = gridDim.x << 2;

#define LOADX(rt_, buf_)                                                      \
    {                                                                         \
        int r_ = (rt_) * 16 + cl;                                             \
        if (r_ >= n_nodes) r_ = n_nodes - 1;                                  \
        const float* p_ = x + (size_t)r_ * D + g * 8;                         \
        _Pragma("unroll")                                                     \
        for (int ks_ = 0; ks_ < 4; ++ks_) {                                   \
            buf_[2 * ks_]     = *reinterpret_cast<const float4*>(p_ + ks_ * 32);     \
            buf_[2 * ks_ + 1] = *reinterpret_cast<const float4*>(p_ + ks_ * 32 + 4); \
        }                                                                     \
    }

#define COMPUTE(rt_, buf_)                                                    \
    {                                                                         \
        f32x4 acc_[8];                                                        \
        _Pragma("unroll")                                                     \
        for (int ct_ = 0; ct_ < 8; ++ct_) acc_[ct_] = (f32x4)(0.f);           \
        _Pragma("unroll")                                                     \
        for (int ks_ = 0; ks_ < 4; ++ks_) {                                   \
            short8 xf_;                                                       \
            unsigned* xu_ = reinterpret_cast<unsigned*>(&xf_);                \
            const float4 a_ = buf_[2 * ks_], b_ = buf_[2 * ks_ + 1];          \
            xu_[0] = pk2(a_.x, a_.y); xu_[1] = pk2(a_.z, a_.w);               \
            xu_[2] = pk2(b_.x, b_.y); xu_[3] = pk2(b_.z, b_.w);               \
            _Pragma("unroll")                                                 \
            for (int ct_ = 0; ct_ < 8; ++ct_)                                 \
                acc_[ct_] = __builtin_amdgcn_mfma_f32_16x16x32_bf16(          \
                    wf[ct_][ks_], xf_, acc_[ct_], 0, 0, 0);                   \
        }                                                                     \
        const int r_ = (rt_) * 16 + cl;                                       \
        if (r_ < n_nodes) {                                                   \
            unsigned* yp_ = y + (size_t)r_ * D2U + g * 2;                     \
            _Pragma("unroll")                                                 \
            for (int ct_ = 0; ct_ < 8; ++ct_) {                               \
                uint2 v2_ = make_uint2(pk2(acc_[ct_][0], acc_[ct_][1]),       \
                                       pk2(acc_[ct_][2], acc_[ct_][3]));      \
                *reinterpret_cast<uint2*>(yp_ + ct_ * 8) = v2_;               \
            }                                                                 \
        }                                                                     \
    }

    int rt = wave;
    if (rt >= ntiles) return;
    float4 bufA[8], bufB[8];
    LOADX(rt, bufA);
    while (true) {
        int nxt = rt + nwaves;
        if (nxt < ntiles) {
            LOADX(nxt, bufB);
            COMPUTE(rt, bufA);
            rt = nxt;
            nxt = rt + nwaves;
            if (nxt < ntiles) {
                LOADX(nxt, bufA);
                COMPUTE(rt, bufB);
                rt = nxt;
            } else { COMPUTE(rt, bufB); break; }
        } else { COMPUTE(rt, bufA); break; }
    }
#undef LOADX
#undef COMPUTE
}

// ---------------------------------------------------------------------------
// Kernel 2: build CSR row_ptr from sorted edge_row.
// ---------------------------------------------------------------------------
__global__ __launch_bounds__(256) void build_rowptr_kernel(
    const int* __restrict__ row, int* __restrict__ ptr, int n_edges, int n_nodes)
{
    int e = blockIdx.x * blockDim.x + threadIdx.x;
    if (e > n_edges) return;
    int lo, hi;                     // set ptr[r] = e for r in (lo, hi]
    if (e == 0)            { lo = -1;               hi = row[0];   }
    else if (e == n_edges) { lo = row[n_edges - 1]; hi = n_nodes;  }
    else {
        lo = row[e - 1];
        hi = row[e];
        if (lo == hi) return;
    }
    for (int r = lo + 1; r <= hi; ++r) ptr[r] = e;
}

// ---------------------------------------------------------------------------
// Kernel 3: out[r,:] = sum_e val[e] * y[col[e],:]   (bf16 gather, fp32 acc)
// One wave per row, lane owns 1 packed uint (2 cols).
// col/val are SCALARIZED (readfirstlane'd bounds -> s_load on lgkmcnt), so
// the vmcnt FIFO holds ONLY gathers. Batch i+1's gathers are issued BEFORE
// consuming batch i (consume waits vmcnt(8), keeping 8 gathers in flight);
// cv for batch i+2 loads after consume, hidden on lgkmcnt. Tail removed via
// scalar-clamped padding (v=0), so all edges take the pipelined path.
// ---------------------------------------------------------------------------
__global__ __launch_bounds__(256) void spmm_kernel(
    const unsigned* __restrict__ yb, const int* __restrict__ ptr,
    const int* __restrict__ col, const float* __restrict__ val,
    float2* __restrict__ out2, int n_nodes)
{
    int gid  = blockIdx.x * blockDim.x + threadIdx.x;
    int r    = gid >> 6;            // one wave per row
    int lane = threadIdx.x & 63;
    if (r >= n_nodes) return;

    const int s = __builtin_amdgcn_readfirstlane(ptr[r]);
    const int e = __builtin_amdgcn_readfirstlane(ptr[r + 1]);
    const int nb = (e - s + 7) >> 3;      // padded batches of 8

    float ax = 0.f, ay = 0.f;

#define SLOAD(bk_, C_, V_)                                           \
    {                                                                \
        const int base_ = s + ((bk_) << 3);                          \
        _Pragma("unroll")                                            \
        for (int k_ = 0; k_ < 8; ++k_) {                             \
            const int idx_ = base_ + k_;                             \
            const int si_  = (idx_ < e) ? idx_ : (e - 1);            \
            C_[k_] = col[si_];                                       \
            const float vv_ = val[si_];                              \
            V_[k_] = (idx_ < e) ? vv_ : 0.f;                         \
        }                                                            \
    }
#define GATHER(C_, U_)                                               \
    {                                                                \
        _Pragma("unroll")                                            \
        for (int k_ = 0; k_ < 8; ++k_)                               \
            U_[k_] = yb[((size_t)C_[k_] << 6) + lane];               \
    }
#define CONSUME(U_, V_)                                              \
    {                                                                \
        _Pragma("unroll")                                            \
        for (int k_ = 0; k_ < 8; ++k_) {                             \
            ax += V_[k_] * bflo(U_[k_]);                             \
            ay += V_[k_] * bfhi(U_[k_]);                             \
        }                                                            \
    }

    if (nb > 0) {
        int      c0[8], c1[8];
        float    v0[8], v1[8];
        unsigned uA[8], uB[8];

        SLOAD(0, c0, v0);
        GATHER(c0, uA);
        if (nb > 1) SLOAD(1, c1, v1);

        int bk = 0;
        while (true) {
            // roles: cur cv = c0/v0, nxt cv = c1/v1, cur gathers = uA
            if (bk + 1 < nb) GATHER(c1, uB);     // issue next BEFORE consume
            CONSUME(uA, v0);                     // waits vmcnt(8): uB in flight
            if (bk + 2 < nb) SLOAD(bk + 2, c0, v0);
            ++bk;
            if (bk >= nb) break;
            // swapped roles
            if (bk + 1 < nb) GATHER(c0, uA);
            CONSUME(uB, v1);
            if (bk + 2 < nb) SLOAD(bk + 2, c1, v1);
            ++bk;
            if (bk >= nb) break;
        }
    }
#undef SLOAD
#undef GATHER
#undef CONSUME

    f32x2 o;
    o.x = ax; o.y = ay;
    __builtin_nontemporal_store(o,
        reinterpret_cast<f32x2*>(out2 + (size_t)r * D2U + lane));
}

// ---------------------------------------------------------------------------
extern "C" void kernel_launch(void* const* d_in, const int* in_sizes, int n_in,
                              void* d_out, int out_size, void* d_ws, size_t ws_size,
                              hipStream_t stream)
{
    const float* x        = (const float*)d_in[0];
    const int*   edge_row = (const int*)  d_in[1];
    const int*   edge_col = (const int*)  d_in[2];
    const float* edge_val = (const float*)d_in[3];
    const float* W        = (const float*)d_in[4];
    float*       out      = (float*)d_out;

    const int n_nodes = in_sizes[0] / D;
    const int n_edges = in_sizes[1];
    const int ntiles  = (n_nodes + 15) / 16;

    // workspace layout: y_bf16 [n_nodes*D2U uint] | row_ptr [(n_nodes+1) i32]
    unsigned* y   = (unsigned*)d_ws;
    int*      ptr = (int*)((char*)d_ws + (size_t)n_nodes * D2U * sizeof(unsigned));

    // 1) y = bf16(x @ W)  (MFMA)
    gemm_mfma_kernel<<<512, 256, 0, stream>>>(x, W, y, n_nodes, ntiles);

    // 2) row_ptr
    {
        int blocks = (n_edges + 1 + 255) / 256;
        build_rowptr_kernel<<<blocks, 256, 0, stream>>>(edge_row, ptr, n_edges, n_nodes);
    }
    // 3) out = A @ y   (one wave per row)
    {
        int rows_per_block = 256 / 64;
        int blocks = (n_nodes + rows_per_block - 1) / rows_per_block;
        spmm_kernel<<<blocks, 256, 0, stream>>>(y, ptr, edge_col, edge_val,
                                                (float2*)out, n_nodes);
    }
}

// Round 6
// 156.395 us; speedup vs baseline: 1.1605x; 1.1605x over previous
//
#include <hip/hip_runtime.h>
#include <hip/hip_bf16.h>

#define D 128            // D_IN == D_OUT
#define D2U 64           // D/2 packed bf16 pairs (uint) per row

typedef __attribute__((ext_vector_type(8))) short  short8;
typedef __attribute__((ext_vector_type(4))) float  f32x4;

// fp32 -> bf16 (RTNE)
__device__ __forceinline__ unsigned f2bf(float f) {
    unsigned u = __float_as_uint(f);
    u += 0x7FFFu + ((u >> 16) & 1u);
    return u >> 16;
}
__device__ __forceinline__ unsigned pk2(float a, float b) {
    return f2bf(a) | (f2bf(b) << 16);
}
__device__ __forceinline__ float bflo(unsigned u) { return __uint_as_float(u << 16); }
__device__ __forceinline__ float bfhi(unsigned u) { return __uint_as_float(u & 0xFFFF0000u); }

// ---------------------------------------------------------------------------
// Kernel 1: y = bf16(x @ W) via MFMA 16x16x32 bf16.  (unchanged from R4)
// ---------------------------------------------------------------------------
__global__ __launch_bounds__(256, 2) void gemm_mfma_kernel(
    const float* __restrict__ x, const float* __restrict__ W,
    unsigned* __restrict__ y, int n_nodes, int ntiles)
{
    __shared__ unsigned short Wt[D * D];   // bf16 [c][k], k XOR-swizzled, 32 KB

    const int t = threadIdx.x;

    // ---- transpose W fp32 [k][c] -> Wt bf16 [c][k] (slot = (k>>3) ^ (c&15))
    {
        const float4* W4 = reinterpret_cast<const float4*>(W);
#pragma unroll
        for (int m = 0; m < 16; ++m) {
            const int idx4 = m * 256 + t;        // float4 index
            const int k  = idx4 >> 5;            // 32 float4 per k-row
            const int c0 = (idx4 & 31) << 2;
            const float4 w = W4[idx4];
            const float wv[4] = {w.x, w.y, w.z, w.w};
#pragma unroll
            for (int i = 0; i < 4; ++i) {
                const int c    = c0 + i;
                const int slot = (k >> 3) ^ (c & 15);
                Wt[c * 128 + slot * 8 + (k & 7)] = (unsigned short)f2bf(wv[i]);
            }
        }
    }
    __syncthreads();

    const int lane = t & 63;
    const int cl   = lane & 15;
    const int g    = lane >> 4;

    // ---- hoist all W fragments (8 col-tiles x 4 k-steps) into registers
    short8 wf[8][4];
#pragma unroll
    for (int ct = 0; ct < 8; ++ct)
#pragma unroll
        for (int ks = 0; ks < 4; ++ks) {
            const int c    = ct * 16 + cl;
            const int slot = (ks * 4 + g) ^ cl;
            wf[ct][ks] = *reinterpret_cast<const short8*>(&Wt[c * 128 + slot * 8]);
        }

    const int wave   = (blockIdx.x << 2) | (t >> 6);
    const int nwaves = gridDim.x << 2;

#define LOADX(rt_, buf_)                                                      \
    {                                                                         \
        int r_ = (rt_) * 16 + cl;                                             \
        if (r_ >= n_nodes) r_ = n_nodes - 1;                                  \
        const float* p_ = x + (size_t)r_ * D + g * 8;                         \
        _Pragma("unroll")                                                     \
        for (int ks_ = 0; ks_ < 4; ++ks_) {                                   \
            buf_[2 * ks_]     = *reinterpret_cast<const float4*>(p_ + ks_ * 32);     \
            buf_[2 * ks_ + 1] = *reinterpret_cast<const float4*>(p_ + ks_ * 32 + 4); \
        }                                                                     \
    }

#define COMPUTE(rt_, buf_)                                                    \
    {                                                                         \
        f32x4 acc_[8];                                                        \
        _Pragma("unroll")                                                     \
        for (int ct_ = 0; ct_ < 8; ++ct_) acc_[ct_] = (f32x4)(0.f);           \
        _Pragma("unroll")                                                     \
        for (int ks_ = 0; ks_ < 4; ++ks_) {                                   \
            short8 xf_;                                                       \
            unsigned* xu_ = reinterpret_cast<unsigned*>(&xf_);                \
            const float4 a_ = buf_[2 * ks_], b_ = buf_[2 * ks_ + 1];          \
            xu_[0] = pk2(a_.x, a_.y); xu_[1] = pk2(a_.z, a_.w);               \
            xu_[2] = pk2(b_.x, b_.y); xu_[3] = pk2(b_.z, b_.w);               \
            _Pragma("unroll")                                                 \
            for (int ct_ = 0; ct_ < 8; ++ct_)                                 \
                acc_[ct_] = __builtin_amdgcn_mfma_f32_16x16x32_bf16(          \
                    wf[ct_][ks_], xf_, acc_[ct_], 0, 0, 0);                   \
        }                                                                     \
        const int r_ = (rt_) * 16 + cl;                                       \
        if (r_ < n_nodes) {                                                   \
            unsigned* yp_ = y + (size_t)r_ * D2U + g * 2;                     \
            _Pragma("unroll")                                                 \
            for (int ct_ = 0; ct_ < 8; ++ct_) {                               \
                uint2 v2_ = make_uint2(pk2(acc_[ct_][0], acc_[ct_][1]),       \
                                       pk2(acc_[ct_][2], acc_[ct_][3]));      \
                *reinterpret_cast<uint2*>(yp_ + ct_ * 8) = v2_;               \
            }                                                                 \
        }                                                                     \
    }

    int rt = wave;
    if (rt >= ntiles) return;
    float4 bufA[8], bufB[8];
    LOADX(rt, bufA);
    while (true) {
        int nxt = rt + nwaves;
        if (nxt < ntiles) {
            LOADX(nxt, bufB);
            COMPUTE(rt, bufA);
            rt = nxt;
            nxt = rt + nwaves;
            if (nxt < ntiles) {
                LOADX(nxt, bufA);
                COMPUTE(rt, bufB);
                rt = nxt;
            } else { COMPUTE(rt, bufB); break; }
        } else { COMPUTE(rt, bufA); break; }
    }
#undef LOADX
#undef COMPUTE
}

// ---------------------------------------------------------------------------
// Kernel 2: build CSR row_ptr from sorted edge_row.
// ---------------------------------------------------------------------------
__global__ __launch_bounds__(256) void build_rowptr_kernel(
    const int* __restrict__ row, int* __restrict__ ptr, int n_edges, int n_nodes)
{
    int e = blockIdx.x * blockDim.x + threadIdx.x;
    if (e > n_edges) return;
    int lo, hi;                     // set ptr[r] = e for r in (lo, hi]
    if (e == 0)            { lo = -1;               hi = row[0];   }
    else if (e == n_edges) { lo = row[n_edges - 1]; hi = n_nodes;  }
    else {
        lo = row[e - 1];
        hi = row[e];
        if (lo == hi) return;
    }
    for (int r = lo + 1; r <= hi; ++r) ptr[r] = e;
}

// ---------------------------------------------------------------------------
// Kernel 3: out[r,:] = sum_e val[e] * y[col[e],:]   (bf16 gather, fp32 acc)
// TWO rows per wave: half = lane>>5 picks the row, hl = lane&31; each lane
// owns a uint2 (4 bf16 cols) -> dwordx2 gathers, 512 B per instruction.
// col/val loaded as ALIGNED int4/float4 on a global 16B grid (head/tail
// masked v=0): 2 VMEM instrs per 4-edge batch, no readfirstlane (low SGPR),
// no shuffles. cv for batch b+1 prefetched before consuming batch b (cv wait
// = vmcnt(2), gather wait is the one real stall; TLP at 8 waves/SIMD hides).
// ---------------------------------------------------------------------------
__global__ __launch_bounds__(256) void spmm_kernel(
    const uint2* __restrict__ yb2, const int* __restrict__ ptr,
    const int* __restrict__ col, const float* __restrict__ val,
    float4* __restrict__ out4, int n_nodes)
{
    const int gid  = blockIdx.x * blockDim.x + threadIdx.x;
    const int w    = gid >> 6;
    const int lane = threadIdx.x & 63;
    const int half = lane >> 5;
    const int hl   = lane & 31;
    const int row  = (w << 1) + half;
    const bool valid = (row < n_nodes);

    int s = 0, e = 0;
    if (valid) { s = ptr[row]; e = ptr[row + 1]; }

    const int base = s & ~3;                       // 16B-aligned batch grid
    const int nb   = valid ? ((e - base + 3) >> 2) : 0;

    float ax = 0.f, ay = 0.f, az = 0.f, aw = 0.f;

    int4   cA, cB;
    float4 vA, vB;

    // PHASE: prefetch cv for batch (b_+1) into (PC_,PV_), then gather+consume
    // batch b_ from (C_,V_). All 4 gathers issued before any FMA.
#define PHASE(b_, C_, V_, PC_, PV_)                                          \
    {                                                                        \
        if ((b_) + 1 < nb) {                                                 \
            const int o_ = base + (((b_) + 1) << 2);                         \
            PC_ = *reinterpret_cast<const int4*>(col + o_);                  \
            PV_ = *reinterpret_cast<const float4*>(val + o_);                \
        }                                                                    \
        const int i0_ = base + ((b_) << 2);                                  \
        const uint2 u0_ = yb2[(size_t)C_.x * 32 + hl];                       \
        const uint2 u1_ = yb2[(size_t)C_.y * 32 + hl];                       \
        const uint2 u2_ = yb2[(size_t)C_.z * 32 + hl];                       \
        const uint2 u3_ = yb2[(size_t)C_.w * 32 + hl];                       \
        const float m0_ = (i0_ + 0 >= s && i0_ + 0 < e) ? V_.x : 0.f;        \
        const float m1_ = (i0_ + 1 >= s && i0_ + 1 < e) ? V_.y : 0.f;        \
        const float m2_ = (i0_ + 2 >= s && i0_ + 2 < e) ? V_.z : 0.f;        \
        const float m3_ = (i0_ + 3 >= s && i0_ + 3 < e) ? V_.w : 0.f;        \
        ax += m0_ * bflo(u0_.x); ay += m0_ * bfhi(u0_.x);                    \
        az += m0_ * bflo(u0_.y); aw += m0_ * bfhi(u0_.y);                    \
        ax += m1_ * bflo(u1_.x); ay += m1_ * bfhi(u1_.x);                    \
        az += m1_ * bflo(u1_.y); aw += m1_ * bfhi(u1_.y);                    \
        ax += m2_ * bflo(u2_.x); ay += m2_ * bfhi(u2_.x);                    \
        az += m2_ * bflo(u2_.y); aw += m2_ * bfhi(u2_.y);                    \
        ax += m3_ * bflo(u3_.x); ay += m3_ * bfhi(u3_.x);                    \
        az += m3_ * bflo(u3_.y); aw += m3_ * bfhi(u3_.y);                    \
    }

    if (nb > 0) {
        cA = *reinterpret_cast<const int4*>(col + base);
        vA = *reinterpret_cast<const float4*>(val + base);
        int b = 0;
        while (true) {
            PHASE(b, cA, vA, cB, vB);
            if (++b >= nb) break;
            PHASE(b, cB, vB, cA, vA);
            if (++b >= nb) break;
        }
    }
#undef PHASE

    if (valid) {
        f32x4 o;
        o.x = ax; o.y = ay; o.z = az; o.w = aw;
        __builtin_nontemporal_store(o,
            reinterpret_cast<f32x4*>(out4 + (size_t)row * 32 + hl));
    }
}

// ---------------------------------------------------------------------------
extern "C" void kernel_launch(void* const* d_in, const int* in_sizes, int n_in,
                              void* d_out, int out_size, void* d_ws, size_t ws_size,
                              hipStream_t stream)
{
    const float* x        = (const float*)d_in[0];
    const int*   edge_row = (const int*)  d_in[1];
    const int*   edge_col = (const int*)  d_in[2];
    const float* edge_val = (const float*)d_in[3];
    const float* W        = (const float*)d_in[4];
    float*       out      = (float*)d_out;

    const int n_nodes = in_sizes[0] / D;
    const int n_edges = in_sizes[1];
    const int ntiles  = (n_nodes + 15) / 16;

    // workspace layout: y_bf16 [n_nodes*D2U uint] | row_ptr [(n_nodes+1) i32]
    unsigned* y   = (unsigned*)d_ws;
    int*      ptr = (int*)((char*)d_ws + (size_t)n_nodes * D2U * sizeof(unsigned));

    // 1) y = bf16(x @ W)  (MFMA)
    gemm_mfma_kernel<<<512, 256, 0, stream>>>(x, W, y, n_nodes, ntiles);

    // 2) row_ptr
    {
        int blocks = (n_edges + 1 + 255) / 256;
        build_rowptr_kernel<<<blocks, 256, 0, stream>>>(edge_row, ptr, n_edges, n_nodes);
    }
    // 3) out = A @ y   (two rows per wave)
    {
        int nwaves = (n_nodes + 1) / 2;
        int blocks = (nwaves + 3) / 4;          // 4 waves per 256-thread block
        spmm_kernel<<<blocks, 256, 0, stream>>>((const uint2*)y, ptr,
                                                edge_col, edge_val,
                                                (float4*)out, n_nodes);
    }
}